// Round 14
// baseline (1095.103 us; speedup 1.0000x reference)
//
#include <hip/hip_runtime.h>
#include <hip/hip_bf16.h>

#define NB 32
#define NS 2048
#define DIM 1024
#define NM (NB*NS)   // 65536 rows
#define CAP 256      // max rescored rows per batch
#define SEL_MARGIN 24.0f

typedef __attribute__((ext_vector_type(8))) short short8;
typedef __attribute__((ext_vector_type(4))) float f32x4;
typedef __attribute__((ext_vector_type(4))) unsigned short us16x4;
typedef unsigned short us16;
typedef unsigned int   u32;
typedef __attribute__((address_space(3))) void lds_void;
typedef __attribute__((address_space(1))) void glb_void;

__device__ __forceinline__ void gload16(const void* g, void* l){
  __builtin_amdgcn_global_load_lds((const glb_void*)g, (lds_void*)l, 16, 0, 0);
}

__device__ __forceinline__ float fast_tanh(float x){
  float e = __builtin_exp2f(x * 2.8853900817779268f); // e^{2x}
  return 1.0f - 2.0f/(e + 1.0f);
}

__device__ __forceinline__ void split_bf16(float x, short &hi, short &lo){
  u32 u = __float_as_uint(x);
  float hf = __uint_as_float(u & 0xFFFF0000u);
  hi = (short)(u >> 16);
  lo = (short)(__float_as_uint(x - hf) >> 16);
}

// ---------------- fused prep: wb images + avec + mask compaction --------------
__global__ void k_prep(const float* __restrict__ wb,
                       const float* __restrict__ kin,
                       const float* __restrict__ wa,
                       const int* __restrict__ mask,
                       char* __restrict__ imgf,
                       char* __restrict__ img1,
                       float* __restrict__ avec,
                       int* __restrict__ cidx,
                       int* __restrict__ cnt,
                       int* __restrict__ sel_count){
  __shared__ float4 kl[256];
  __shared__ int tc[256];
  __shared__ int tot;
  const int h = blockIdx.x, t = threadIdx.x;
  if(h == 0 && t < NB) sel_count[t] = 0;
  if(h < 1024){
    // phase-2 B image: 16B slot = ((kt*64 + ct16)*2 + hl)*64 + lane
    const int tid = h*256 + t;
    const int kt   = tid >> 13;
    const int ct16 = (tid >> 7) & 63;
    const int hl   = (tid >> 6) & 1;
    const int lane = tid & 63;
    const int col  = ct16*16 + (lane & 15);
    const int k0   = kt*32 + (lane >> 4)*8;
    const float* src = wb + (size_t)col*DIM + k0;
    float4 v0 = *(const float4*)src;
    float4 v1 = *(const float4*)(src + 4);
    float fv[8] = {v0.x,v0.y,v0.z,v0.w,v1.x,v1.y,v1.z,v1.w};
    short8 out;
    #pragma unroll
    for(int j=0;j<8;j++){
      short hi,lo; split_bf16(fv[j],hi,lo);
      out[j] = hl ? lo : hi;
    }
    *(short8*)(imgf + (size_t)tid*16) = out;
  } else if(h < 1536){
    // phase-1 B image = [kt(32)][cb(4)][16KB]; byte B: row=B>>7, inner=B&127,
    // ix = inner ^ ((row&7)<<4): col = cb*256 + (ix>>6)*128 + row,
    // k = kt*32 + ((ix>>4)&3)*8 + (B&15)/2 (hi bf16)
    const int tid = (h-1024)*256 + t;
    const int tile = tid >> 10;
    const int kt = tile >> 2, cb = tile & 3;
    const int byt = (tid & 1023) * 16;
    const int row = byt >> 7, inner = byt & 127;
    const int ix = inner ^ ((row & 7) << 4);
    const int colhi = ix >> 6, lkk = (ix >> 4) & 3;
    const int col = cb*256 + colhi*128 + row;
    const float* src = wb + (size_t)col*DIM + kt*32 + lkk*8;
    float4 v0 = *(const float4*)src;
    float4 v1 = *(const float4*)(src + 4);
    float fv[8] = {v0.x,v0.y,v0.z,v0.w,v1.x,v1.y,v1.z,v1.w};
    short8 out;
    #pragma unroll
    for(int j=0;j<8;j++) out[j] = (short)(__float_as_uint(fv[j]) >> 16);
    *(short8*)(img1 + (size_t)tid*16) = out;
  } else if(h < 1664){
    const int hb = h - 1536;
    const int b = hb >> 2, oc = hb & 3;
    kl[t] = *(const float4*)(kin + b*DIM + t*4);
    __syncthreads();
    const int o = oc*256 + t;
    const float4* wrow = (const float4*)(wa + (size_t)o*DIM);
    float acc = 0.f;
    for(int i=0;i<256;i++){
      float4 wv = wrow[i]; float4 kk = kl[i];
      acc += wv.x*kk.x + wv.y*kk.y + wv.z*kk.z + wv.w*kk.w;
    }
    avec[b*DIM + o] = acc;
  } else {
    // ---- stable compaction of unmasked rows for batch b ----
    const int b = h - 1664;
    int mv[8]; int c = 0;
    #pragma unroll
    for(int e=0;e<8;e++){ mv[e] = mask[b*NS + t*8 + e]; c += (mv[e] ? 1 : 0); }
    tc[t] = c;
    __syncthreads();
    for(int d=1; d<256; d<<=1){          // Hillis-Steele inclusive scan
      int v = tc[t];
      int add = (t >= d) ? tc[t-d] : 0;
      __syncthreads();
      tc[t] = v + add;
      __syncthreads();
    }
    const int excl = tc[t] - c;
    if(t == 255) tot = tc[t];
    __syncthreads();
    int pos = excl;
    #pragma unroll
    for(int e=0;e<8;e++){
      if(mv[e]) cidx[b*NS + (pos++)] = t*8 + e;
    }
    const int total = tot;
    if(t == 0) cnt[b] = total;
    for(int p = total + t; p < NS; p += 256) cidx[b*NS + p] = 0;  // safe pad
  }
}

// ---------------- phase-1: 1-pass truncated-bf16 GEMM over COMPACTED rows -----
// R13 structure + R14 delta: Abuf shrunk [128][40]->[128][32] (64B rows, 2-bit
// XOR key) so LDS = 40960 = 160K/4 exactly -> 4 blocks/CU residency.
__global__ __launch_bounds__(256,4)
void k_gemm_approx(const float* __restrict__ xs,
                   const char* __restrict__ img1,
                   const float* __restrict__ avec,
                   const float* __restrict__ energy,
                   const int* __restrict__ cidx,
                   const int* __restrict__ cnt,
                   float* __restrict__ partial){
  __shared__ us16 Abuf[128][32];      // hi only; 64B rows, 2-bit XOR swizzle
  __shared__ us16 Bbuf[2][128][64];   // 2 x 16KB, filled by global_load_lds

  const int h = blockIdx.x;                   // 2048 blocks
  int bidx, tile, cb;
  if(h < 1152){                               // dense: 32 b x 9 t x 4 cb
    const int q = h >> 3;                     // 0..143
    cb = q & 3;
    const int pair = (h & 7)*36 + (q >> 2);   // XCD h%8 owns pairs [36x,36x+36)
    bidx = pair / 9; tile = pair % 9;
  } else {                                    // rare region: tiles 9..15
    const int h2 = h - 1152;
    bidx = h2 / 28; tile = 9 + ((h2 % 28) >> 2); cb = h2 & 3;
  }
  if(tile*128 >= cnt[bidx]) return;           // tile beyond unmasked count
  const int t  = threadIdx.x;
  const int w  = t >> 6, lane = t & 63;
  const int wr = w >> 1, wc = w & 1;          // wave tile: 64 rows x 128 cols
  const int lm = lane & 15, lk = lane >> 4;
  const int sr = t >> 1, sh = t & 1;

  const int orig = cidx[bidx*NS + tile*128 + sr];   // gathered source row
  const float* ap = xs + ((size_t)bidx*NS + orig)*DIM + sh*16;
  const char*  bsrc = img1;                   // + (kt*4+cb)*16384

  const char* a_rd = (const char*)&Abuf[0][0] + (wr*64 + lm)*64 + ((lk*16) ^ ((lm&3)<<4));
  const int boff = (wc*64 + lk*16) ^ ((lm&7)<<4);

  f32x4 acc[4][8];
  #pragma unroll
  for(int m=0;m<4;m++)
    #pragma unroll
    for(int n=0;n<8;n++) acc[m][n] = (f32x4){0.f,0.f,0.f,0.f};

  // prologue: A(0) regs FIRST (oldest in FIFO), then B(0) gloads
  float4 ar0 = *(const float4*)(ap+0),  ar1 = *(const float4*)(ap+4);
  float4 ar2 = *(const float4*)(ap+8),  ar3 = *(const float4*)(ap+12);
  {
    const char* gs = bsrc + (size_t)cb*16384 + t*16;
    char* ld = (char*)&Bbuf[0][0][0] + t*16;
    #pragma unroll
    for(int c=0;c<4;c++) gload16(gs + c*4096, ld + c*4096);
  }

  for(int kt=0; kt<32; kt++){
    const int cur = kt & 1;
    // bar1: all waves' frag reads of tile kt-1 done (lgkm only — NO vmem drain)
    asm volatile("s_waitcnt lgkmcnt(0)" ::: "memory");
    __builtin_amdgcn_sched_barrier(0);
    __builtin_amdgcn_s_barrier();
    {   // truncate-store A(kt) from ar into 64B-row swizzled layout
      float fv[16];
      *(float4*)(fv+0)=ar0; *(float4*)(fv+4)=ar1;
      *(float4*)(fv+8)=ar2; *(float4*)(fv+12)=ar3;
      short8 h0, h1;
      #pragma unroll
      for(int j=0;j<8;j++){ h0[j] = (short)(__float_as_uint(fv[j])>>16);
                            h1[j] = (short)(__float_as_uint(fv[8+j])>>16); }
      char* abase = (char*)&Abuf[0][0] + sr*64;
      const int swz = (sr & 3) << 4;
      *(short8*)(abase + ((sh*32     ) ^ swz)) = h0;
      *(short8*)(abase + ((sh*32 + 16) ^ swz)) = h1;
    }
    if(kt < 31){
      const float* a2 = ap + (kt+1)*32;   // A(kt+1) regs first (oldest)
      ar0 = *(const float4*)(a2+0);  ar1 = *(const float4*)(a2+4);
      ar2 = *(const float4*)(a2+8);  ar3 = *(const float4*)(a2+12);
      {                                   // then B(kt+1) gloads
        const char* gs = bsrc + (size_t)((kt+1)*4 + cb)*16384 + t*16;
        char* ld = (char*)&Bbuf[cur^1][0][0] + t*16;
        #pragma unroll
        for(int c=0;c<4;c++) gload16(gs + c*4096, ld + c*4096);
      }
      // FIFO: [B(kt)4, A(kt+1)4, B(kt+1)4] -> vmcnt(8): B(kt) landed,
      // next-tile loads stay in flight. lgkm(0) = A ds_writes visible.
      asm volatile("s_waitcnt vmcnt(8) lgkmcnt(0)" ::: "memory");
    } else {
      asm volatile("s_waitcnt vmcnt(0) lgkmcnt(0)" ::: "memory");
    }
    __builtin_amdgcn_sched_barrier(0);
    __builtin_amdgcn_s_barrier();       // bar2: tile kt fully in LDS

    short8 fa[4], fb[8];
    const char* bb = (const char*)&Bbuf[cur][0][0] + lm*128 + boff;
    #pragma unroll
    for(int m=0;m<4;m++) fa[m] = *(const short8*)(a_rd + m*1024);
    #pragma unroll
    for(int n=0;n<8;n++) fb[n] = *(const short8*)(bb + n*2048);
    #pragma unroll
    for(int m=0;m<4;m++)
      #pragma unroll
      for(int n=0;n<8;n++)
        acc[m][n] = __builtin_amdgcn_mfma_f32_16x16x32_bf16(fa[m], fb[n], acc[m][n], 0,0,0);
  }

  // epilogue: partial[cb*2+wc][compacted row] over wave's 128 cols
  float av[8], ev[8];
  #pragma unroll
  for(int n=0;n<8;n++){
    const int col = cb*256 + wc*128 + n*16 + lm;
    av[n] = avec[bidx*DIM + col];
    ev[n] = energy[col];
  }
  #pragma unroll
  for(int m=0;m<4;m++){
    float rs[4];
    #pragma unroll
    for(int j=0;j<4;j++){
      float s = 0.f;
      #pragma unroll
      for(int n=0;n<8;n++) s += ev[n]*fast_tanh(av[n] + acc[m][n][j]);
      s += __shfl_xor(s,1); s += __shfl_xor(s,2);
      s += __shfl_xor(s,4); s += __shfl_xor(s,8);
      rs[j] = s;
    }
    if(lm == 0){
      float4 st = {rs[0], rs[1], rs[2], rs[3]};
      *(float4*)(partial + (size_t)(cb*2+wc)*NM + bidx*NS + tile*128 + wr*64 + m*16 + lk*4) = st;
    }
  }
}

// ---------------- select over compacted rows; scatter scores to orig ids ------
__global__ void k_select(const float* __restrict__ partial,
                         const int* __restrict__ cidx,
                         const int* __restrict__ cnt,
                         float* __restrict__ scores,
                         int* __restrict__ sel_count,
                         int* __restrict__ sel_list){
  const int b = blockIdx.x, t = threadIdx.x;
  const int w = t >> 6, lane = t & 63;
  __shared__ float red[4];
  const int cnt_b = cnt[b];
  float sv[8]; int orig[8];
  float m = -3.4e38f;
  #pragma unroll
  for(int j=0;j<8;j++){
    const int i = j*256 + t;                  // compacted index
    if(i < cnt_b){
      float s = 0.f;
      #pragma unroll
      for(int c=0;c<8;c++) s += partial[(size_t)c*NM + b*NS + i];
      sv[j] = s;
      orig[j] = cidx[b*NS + i];
      scores[b*NS + orig[j]] = s;             // all compacted rows are unmasked
      if(s > m) m = s;
    } else { sv[j] = -3.4e38f; orig[j] = -1; }
  }
  #pragma unroll
  for(int off=1; off<64; off<<=1) m = fmaxf(m, __shfl_xor(m, off));
  if(lane==0) red[w] = m;
  __syncthreads();
  m = fmaxf(fmaxf(red[0],red[1]), fmaxf(red[2],red[3]));
  const float thr = m - SEL_MARGIN;
  #pragma unroll
  for(int j=0;j<8;j++){
    if(orig[j] >= 0 && sv[j] > thr){
      int slot = atomicAdd(&sel_count[b], 1);
      if(slot < CAP) sel_list[b*CAP + slot] = orig[j];
    }
  }
}

// ---------------- phase-2: exact 3-pass rescoring of selected rows ------------
__global__ __launch_bounds__(256)
void k_phase2(const float* __restrict__ xs,
              const char* __restrict__ imgf,
              const float* __restrict__ avec,
              const float* __restrict__ energy,
              const int* __restrict__ sel_count,
              const int* __restrict__ sel_list,
              float* __restrict__ p2buf){
  __shared__ us16 A2[32][80];     // hi bytes [0,64), lo at +80, row stride 160B
  __shared__ float s2[4][32];
  const int b = blockIdx.x >> 4, cb = blockIdx.x & 15;
  const int t = threadIdx.x, w = t >> 6, lane = t & 63;
  const int lm = lane & 15, lk = lane >> 4;
  const int ct = cb*4 + w;                    // ct16 index 0..63
  const int col = ct*16 + lm;
  const float av  = avec[b*DIM + col];
  const float evv = energy[col];
  char* lds = (char*)&A2[0][0];
  const int count = min(sel_count[b], CAP);
  const int ri = t >> 3, seg = t & 7;
  // 2-bit XOR key: must stay inside the 64-byte hi field (R6 lesson)
  const int wbyte = ri*160 + ((seg*8) ^ ((ri&3)<<4));
  const char* a_rd = lds + lm*160 + ((lk*16) ^ ((lm&3)<<4));

  for(int c0 = 0; c0 < count; c0 += 32){
    const int li = c0 + ri;
    const int row = sel_list[b*CAP + min(li, count-1)];
    const float* rp = xs + ((size_t)b*NS + row)*DIM + seg*4;
    f32x4 acc[2];
    acc[0] = (f32x4){0.f,0.f,0.f,0.f};
    acc[1] = (f32x4){0.f,0.f,0.f,0.f};
    for(int kt=0; kt<32; kt++){
      __syncthreads();                        // prior kt's frag reads consumed
      float4 v = *(const float4*)(rp + kt*32);
      float fv[4] = {v.x, v.y, v.z, v.w};
      us16x4 hi, lo;
      #pragma unroll
      for(int e=0;e<4;e++){
        short a, l; split_bf16(fv[e], a, l);
        hi[e] = (us16)a; lo[e] = (us16)l;
      }
      *(us16x4*)(lds + wbyte)      = hi;
      *(us16x4*)(lds + wbyte + 80) = lo;
      __syncthreads();
      const char* fbb = imgf + ((size_t)(kt*64 + ct)*2)*1024 + lane*16;
      short8 bh = *(const short8*)(fbb);
      short8 bl = *(const short8*)(fbb + 1024);
      short8 fah[2], fal[2];
      #pragma unroll
      for(int m=0;m<2;m++){
        fah[m] = *(const short8*)(a_rd + m*2560);
        fal[m] = *(const short8*)(a_rd + m*2560 + 80);
      }
      #pragma unroll
      for(int m=0;m<2;m++)
        acc[m] = __builtin_amdgcn_mfma_f32_16x16x32_bf16(fah[m], bh, acc[m], 0,0,0);
      #pragma unroll
      for(int m=0;m<2;m++)
        acc[m] = __builtin_amdgcn_mfma_f32_16x16x32_bf16(fah[m], bl, acc[m], 0,0,0);
      #pragma unroll
      for(int m=0;m<2;m++)
        acc[m] = __builtin_amdgcn_mfma_f32_16x16x32_bf16(fal[m], bh, acc[m], 0,0,0);
    }
    float s[2][4];
    #pragma unroll
    for(int m=0;m<2;m++)
      #pragma unroll
      for(int j=0;j<4;j++){
        float v = evv * fast_tanh(av + acc[m][j]);
        v += __shfl_xor(v,1); v += __shfl_xor(v,2);
        v += __shfl_xor(v,4); v += __shfl_xor(v,8);
        s[m][j] = v;
      }
    __syncthreads();
    if(lm == 0){
      #pragma unroll
      for(int m=0;m<2;m++)
        #pragma unroll
        for(int j=0;j<4;j++) s2[w][m*16 + lk*4 + j] = s[m][j];
    }
    __syncthreads();
    if(t < 32){
      float sum = s2[0][t] + s2[1][t] + s2[2][t] + s2[3][t];
      p2buf[((size_t)b*16 + cb)*CAP + c0 + t] = sum;
    }
  }
}

// ------ masked softmax + exact-score scatter + deterministic significant list -
__global__ void k_softmax(const float* __restrict__ scores,
                          const float* __restrict__ p2buf,
                          const int* __restrict__ sel_count,
                          const int* __restrict__ sel_list,
                          const int* __restrict__ mask,
                          float* __restrict__ attn,
                          int* __restrict__ slist2,
                          float* __restrict__ sval2,
                          int* __restrict__ scount2){
  const int b = blockIdx.x, t = threadIdx.x;
  const int w = t >> 6, lane = t & 63;
  __shared__ float sc[NS];      // 8KB: corrected scores
  __shared__ float red[4];
  __shared__ int tc[256];
  __shared__ int tot;
  #pragma unroll
  for(int j=0;j<8;j++) sc[j*256+t] = scores[b*NS + j*256 + t];
  __syncthreads();
  const int count = min(sel_count[b], CAP);
  for(int s0 = t; s0 < count; s0 += 256){
    float s = 0.f;
    #pragma unroll
    for(int c=0;c<16;c++) s += p2buf[((size_t)b*16 + c)*CAP + s0];
    sc[sel_list[b*CAP + s0]] = s;
  }
  __syncthreads();
  float sv[8]; int mv[8];
  float m = -3.4e38f;
  #pragma unroll
  for(int j=0;j<8;j++){
    const int i = j*256 + t;
    sv[j] = sc[i];
    mv[j] = mask[b*NS + i];
    if(mv[j] && sv[j] > m) m = sv[j];
  }
  #pragma unroll
  for(int off=1; off<64; off<<=1) m = fmaxf(m, __shfl_xor(m, off));
  if(lane==0) red[w] = m;
  __syncthreads();
  m = fmaxf(fmaxf(red[0],red[1]), fmaxf(red[2],red[3]));
  __syncthreads();
  float ev[8]; float l = 0.f;
  #pragma unroll
  for(int j=0;j<8;j++){
    ev[j] = mv[j] ? __builtin_exp2f((sv[j]-m)*1.4426950408889634f) : 0.f;
    l += ev[j];
  }
  #pragma unroll
  for(int off=1; off<64; off<<=1) l += __shfl_xor(l, off);
  if(lane==0) red[w] = l;
  __syncthreads();
  l = red[0]+red[1]+red[2]+red[3];
  const float inv = 1.0f/l;
  // write attn + deterministic ordered list of significant rows (attn > 1e-9)
  float av8[8]; int sig[8]; int c = 0;
  #pragma unroll
  for(int j=0;j<8;j++){
    av8[j] = ev[j]*inv;
    attn[b*NS + j*256 + t] = av8[j];
    sig[j] = (av8[j] > 1e-9f) ? 1 : 0;
    c += sig[j];
  }
  tc[t] = c;
  __syncthreads();
  for(int d=1; d<256; d<<=1){            // Hillis-Steele inclusive scan
    int v = tc[t];
    int add = (t >= d) ? tc[t-d] : 0;
    __syncthreads();
    tc[t] = v + add;
    __syncthreads();
  }
  const int excl = tc[t] - c;
  if(t == 255) tot = tc[t];
  __syncthreads();
  int pos = excl;
  #pragma unroll
  for(int j=0;j<8;j++){
    if(sig[j]){
      slist2[b*NS + pos] = j*256 + t;
      sval2 [b*NS + pos] = av8[j];
      pos++;
    }
  }
  if(t == 0) scount2[b] = tot;
}

// ---- ctx over significant rows (deterministic order), 128 blocks -------------
// block = (b, ch): cols ch*256..+256; per-output-d summation order = j ascending
// (bit-identical to the 32-block version; column split doesn't reorder sums)
__global__ void k_ctx(const int* __restrict__ slist2,
                      const float* __restrict__ sval2,
                      const int* __restrict__ scount2,
                      const float* __restrict__ xs,
                      float* __restrict__ ctx){
  const int b = blockIdx.x >> 2, ch = blockIdx.x & 3;
  const int t = threadIdx.x;
  __shared__ int   rows[NS];    // 8KB
  __shared__ float aw[NS];      // 8KB
  const int n = scount2[b];
  for(int i = t; i < n; i += 256){
    rows[i] = slist2[b*NS + i];
    aw[i]   = sval2 [b*NS + i];
  }
  __syncthreads();
  float acc = 0.f;
  const int col = ch*256 + t;
  const float* xb = xs + (size_t)b*NS*DIM + col;
  for(int j=0;j<n;j++){
    acc += aw[j] * xb[(size_t)rows[j]*DIM];
  }
  ctx[b*DIM + col] = acc;
}

extern "C" void kernel_launch(void* const* d_in, const int* in_sizes, int n_in,
                              void* d_out, int out_size, void* d_ws, size_t ws_size,
                              hipStream_t stream) {
  const float* kin    = (const float*)d_in[0];   // [32,1024]
  const float* xs     = (const float*)d_in[1];   // [32,2048,1024]
  const int*   mask   = (const int*)d_in[2];     // [32,2048]
  const float* wa     = (const float*)d_in[3];   // [1024,1024]
  const float* wb     = (const float*)d_in[4];   // [1024,1024]
  const float* energy = (const float*)d_in[5];   // [1024]
  float* out  = (float*)d_out;
  float* ctx  = out;            // [32,1024]
  float* attn = out + NB*DIM;   // [32,2048]

  char* ws = (char*)d_ws;
  float* partial   = (float*)(ws);                       // 2 MB    @ 0
  float* avec      = (float*)(ws + 2097152);             // 128 KB
  float* scores    = (float*)(ws + 2228224);             // 256 KB
  int*   slist2    = (int*)(ws + 2490368);               // 256 KB
  float* sval2     = (float*)(ws + 2752512);             // 256 KB
  int*   scount2   = (int*)(ws + 3014656);               // 128 B
  char*  imgf      = ws + 3538944;                       // 4 MB (frag hi/lo)
  char*  img1      = ws + 7733248;                       // 2 MB (gload hi, BK=32)
  int*   sel_count = (int*)(ws + 9830400);               // 128 B
  int*   sel_list  = (int*)(ws + 9830528);               // 32 KB
  float* p2buf     = (float*)(ws + 9863296);             // 512 KB
  int*   cidx      = (int*)(ws + 10387584);              // 256 KB
  int*   cnt       = (int*)(ws + 10649728);              // 128 B

  k_prep       <<<1696, 256, 0, stream>>>(wb, kin, wa, mask, imgf, img1, avec,
                                          cidx, cnt, sel_count);
  k_gemm_approx<<<2048, 256, 0, stream>>>(xs, img1, avec, energy, cidx, cnt, partial);
  k_select     <<<NB, 256, 0, stream>>>(partial, cidx, cnt, scores, sel_count, sel_list);
  k_phase2     <<<512, 256, 0, stream>>>(xs, imgf, avec, energy, sel_count, sel_list, p2buf);
  k_softmax    <<<NB, 256, 0, stream>>>(scores, p2buf, sel_count, sel_list, mask, attn,
                                        slist2, sval2, scount2);
  k_ctx        <<<128, 256, 0, stream>>>(slist2, sval2, scount2, xs, ctx);
}

// Round 15
// 255.578 us; speedup vs baseline: 4.2848x; 4.2848x over previous
//
#include <hip/hip_runtime.h>
#include <hip/hip_bf16.h>

#define NB 32
#define NS 2048
#define DIM 1024
#define NM (NB*NS)   // 65536 rows
#define CAP 256      // max rescored rows per batch
#define SEL_MARGIN 24.0f

typedef __attribute__((ext_vector_type(8))) short short8;
typedef __attribute__((ext_vector_type(4))) float f32x4;
typedef __attribute__((ext_vector_type(4))) unsigned short us16x4;
typedef unsigned short us16;
typedef unsigned int   u32;
typedef __attribute__((address_space(3))) void lds_void;
typedef __attribute__((address_space(1))) void glb_void;

__device__ __forceinline__ void gload16(const void* g, void* l){
  __builtin_amdgcn_global_load_lds((const glb_void*)g, (lds_void*)l, 16, 0, 0);
}

__device__ __forceinline__ float fast_tanh(float x){
  float e = __builtin_exp2f(x * 2.8853900817779268f); // e^{2x}
  return 1.0f - 2.0f/(e + 1.0f);
}

__device__ __forceinline__ void split_bf16(float x, short &hi, short &lo){
  u32 u = __float_as_uint(x);
  float hf = __uint_as_float(u & 0xFFFF0000u);
  hi = (short)(u >> 16);
  lo = (short)(__float_as_uint(x - hf) >> 16);
}

// ---------------- fused prep: wb images + avec + mask compaction --------------
__global__ void k_prep(const float* __restrict__ wb,
                       const float* __restrict__ kin,
                       const float* __restrict__ wa,
                       const int* __restrict__ mask,
                       char* __restrict__ imgf,
                       char* __restrict__ img1,
                       float* __restrict__ avec,
                       int* __restrict__ cidx,
                       int* __restrict__ cnt,
                       int* __restrict__ sel_count){
  __shared__ float4 kl[256];
  __shared__ int tc[256];
  __shared__ int tot;
  const int h = blockIdx.x, t = threadIdx.x;
  if(h == 0 && t < NB) sel_count[t] = 0;
  if(h < 1024){
    // phase-2 B image: 16B slot = ((kt*64 + ct16)*2 + hl)*64 + lane
    const int tid = h*256 + t;
    const int kt   = tid >> 13;
    const int ct16 = (tid >> 7) & 63;
    const int hl   = (tid >> 6) & 1;
    const int lane = tid & 63;
    const int col  = ct16*16 + (lane & 15);
    const int k0   = kt*32 + (lane >> 4)*8;
    const float* src = wb + (size_t)col*DIM + k0;
    float4 v0 = *(const float4*)src;
    float4 v1 = *(const float4*)(src + 4);
    float fv[8] = {v0.x,v0.y,v0.z,v0.w,v1.x,v1.y,v1.z,v1.w};
    short8 out;
    #pragma unroll
    for(int j=0;j<8;j++){
      short hi,lo; split_bf16(fv[j],hi,lo);
      out[j] = hl ? lo : hi;
    }
    *(short8*)(imgf + (size_t)tid*16) = out;
  } else if(h < 1536){
    // phase-1 B image = [kt(32)][cb(4)][16KB]; byte B: row=B>>7, inner=B&127,
    // ix = inner ^ ((row&7)<<4): col = cb*256 + (ix>>6)*128 + row,
    // k = kt*32 + ((ix>>4)&3)*8 + (B&15)/2 (hi bf16)
    const int tid = (h-1024)*256 + t;
    const int tile = tid >> 10;
    const int kt = tile >> 2, cb = tile & 3;
    const int byt = (tid & 1023) * 16;
    const int row = byt >> 7, inner = byt & 127;
    const int ix = inner ^ ((row & 7) << 4);
    const int colhi = ix >> 6, lkk = (ix >> 4) & 3;
    const int col = cb*256 + colhi*128 + row;
    const float* src = wb + (size_t)col*DIM + kt*32 + lkk*8;
    float4 v0 = *(const float4*)src;
    float4 v1 = *(const float4*)(src + 4);
    float fv[8] = {v0.x,v0.y,v0.z,v0.w,v1.x,v1.y,v1.z,v1.w};
    short8 out;
    #pragma unroll
    for(int j=0;j<8;j++) out[j] = (short)(__float_as_uint(fv[j]) >> 16);
    *(short8*)(img1 + (size_t)tid*16) = out;
  } else if(h < 1664){
    const int hb = h - 1536;
    const int b = hb >> 2, oc = hb & 3;
    kl[t] = *(const float4*)(kin + b*DIM + t*4);
    __syncthreads();
    const int o = oc*256 + t;
    const float4* wrow = (const float4*)(wa + (size_t)o*DIM);
    float acc = 0.f;
    for(int i=0;i<256;i++){
      float4 wv = wrow[i]; float4 kk = kl[i];
      acc += wv.x*kk.x + wv.y*kk.y + wv.z*kk.z + wv.w*kk.w;
    }
    avec[b*DIM + o] = acc;
  } else {
    // ---- stable compaction of unmasked rows for batch b ----
    const int b = h - 1664;
    int mv[8]; int c = 0;
    #pragma unroll
    for(int e=0;e<8;e++){ mv[e] = mask[b*NS + t*8 + e]; c += (mv[e] ? 1 : 0); }
    tc[t] = c;
    __syncthreads();
    for(int d=1; d<256; d<<=1){          // Hillis-Steele inclusive scan
      int v = tc[t];
      int add = (t >= d) ? tc[t-d] : 0;
      __syncthreads();
      tc[t] = v + add;
      __syncthreads();
    }
    const int excl = tc[t] - c;
    if(t == 255) tot = tc[t];
    __syncthreads();
    int pos = excl;
    #pragma unroll
    for(int e=0;e<8;e++){
      if(mv[e]) cidx[b*NS + (pos++)] = t*8 + e;
    }
    const int total = tot;
    if(t == 0) cnt[b] = total;
    for(int p = total + t; p < NS; p += 256) cidx[b*NS + p] = 0;  // safe pad
  }
}

// ---------------- phase-1: 1-pass truncated-bf16 GEMM over COMPACTED rows -----
// R13-verified configuration (best measured: 175us, MfmaUtil 17, no spill).
// 2 blocks/CU is register-floor-bound: 104 VGPR + 128 acc AGPR ~= 232/wave
// (gfx950 unified file) -> 2 waves/SIMD. Do NOT add __launch_bounds__ > 2
// (R10/R14 lesson: allocator cap below 232 spills the accumulator).
__global__ __launch_bounds__(256,2)
void k_gemm_approx(const float* __restrict__ xs,
                   const char* __restrict__ img1,
                   const float* __restrict__ avec,
                   const float* __restrict__ energy,
                   const int* __restrict__ cidx,
                   const int* __restrict__ cnt,
                   float* __restrict__ partial){
  __shared__ us16 Abuf[128][40];      // hi only; row stride 80B
  __shared__ us16 Bbuf[2][128][64];   // 2 x 16KB, filled by global_load_lds

  const int h = blockIdx.x;                   // 2048 blocks
  int bidx, tile, cb;
  if(h < 1152){                               // dense: 32 b x 9 t x 4 cb
    const int q = h >> 3;                     // 0..143
    cb = q & 3;
    const int pair = (h & 7)*36 + (q >> 2);   // XCD h%8 owns pairs [36x,36x+36)
    bidx = pair / 9; tile = pair % 9;
  } else {                                    // rare region: tiles 9..15
    const int h2 = h - 1152;
    bidx = h2 / 28; tile = 9 + ((h2 % 28) >> 2); cb = h2 & 3;
  }
  if(tile*128 >= cnt[bidx]) return;           // tile beyond unmasked count
  const int t  = threadIdx.x;
  const int w  = t >> 6, lane = t & 63;
  const int wr = w >> 1, wc = w & 1;          // wave tile: 64 rows x 128 cols
  const int lm = lane & 15, lk = lane >> 4;
  const int sr = t >> 1, sh = t & 1;

  const int orig = cidx[bidx*NS + tile*128 + sr];   // gathered source row
  const float* ap = xs + ((size_t)bidx*NS + orig)*DIM + sh*16;
  const char*  bsrc = img1;                   // + (kt*4+cb)*16384

  const char* a_rd = (const char*)&Abuf[0][0] + (wr*64 + lm)*80 + ((lk*16) ^ ((lm&3)<<4));
  const int boff = (wc*64 + lk*16) ^ ((lm&7)<<4);

  f32x4 acc[4][8];
  #pragma unroll
  for(int m=0;m<4;m++)
    #pragma unroll
    for(int n=0;n<8;n++) acc[m][n] = (f32x4){0.f,0.f,0.f,0.f};

  // prologue: A(0) regs FIRST (oldest in FIFO), then B(0) gloads
  float4 ar0 = *(const float4*)(ap+0),  ar1 = *(const float4*)(ap+4);
  float4 ar2 = *(const float4*)(ap+8),  ar3 = *(const float4*)(ap+12);
  {
    const char* gs = bsrc + (size_t)cb*16384 + t*16;
    char* ld = (char*)&Bbuf[0][0][0] + t*16;
    #pragma unroll
    for(int c=0;c<4;c++) gload16(gs + c*4096, ld + c*4096);
  }

  for(int kt=0; kt<32; kt++){
    const int cur = kt & 1;
    // bar1: all waves' frag reads of tile kt-1 done (lgkm only — NO vmem drain)
    asm volatile("s_waitcnt lgkmcnt(0)" ::: "memory");
    __builtin_amdgcn_sched_barrier(0);
    __builtin_amdgcn_s_barrier();
    {   // truncate-store A(kt) from ar
      float fv[16];
      *(float4*)(fv+0)=ar0; *(float4*)(fv+4)=ar1;
      *(float4*)(fv+8)=ar2; *(float4*)(fv+12)=ar3;
      short8 h0, h1;
      #pragma unroll
      for(int j=0;j<8;j++){ h0[j] = (short)(__float_as_uint(fv[j])>>16);
                            h1[j] = (short)(__float_as_uint(fv[8+j])>>16); }
      char* abase = (char*)&Abuf[0][0] + sr*80;
      const int swz = (sr & 3) << 4;
      *(short8*)(abase + ((sh*32     ) ^ swz)) = h0;
      *(short8*)(abase + ((sh*32 + 16) ^ swz)) = h1;
    }
    if(kt < 31){
      const float* a2 = ap + (kt+1)*32;   // A(kt+1) regs first (oldest)
      ar0 = *(const float4*)(a2+0);  ar1 = *(const float4*)(a2+4);
      ar2 = *(const float4*)(a2+8);  ar3 = *(const float4*)(a2+12);
      {                                   // then B(kt+1) gloads
        const char* gs = bsrc + (size_t)((kt+1)*4 + cb)*16384 + t*16;
        char* ld = (char*)&Bbuf[cur^1][0][0] + t*16;
        #pragma unroll
        for(int c=0;c<4;c++) gload16(gs + c*4096, ld + c*4096);
      }
      // FIFO: [B(kt)4, A(kt+1)4, B(kt+1)4] -> vmcnt(8): B(kt) landed,
      // next-tile loads stay in flight. lgkm(0) = A ds_writes visible.
      asm volatile("s_waitcnt vmcnt(8) lgkmcnt(0)" ::: "memory");
    } else {
      asm volatile("s_waitcnt vmcnt(0) lgkmcnt(0)" ::: "memory");
    }
    __builtin_amdgcn_sched_barrier(0);
    __builtin_amdgcn_s_barrier();       // bar2: tile kt fully in LDS

    short8 fa[4], fb[8];
    const char* bb = (const char*)&Bbuf[cur][0][0] + lm*128 + boff;
    #pragma unroll
    for(int m=0;m<4;m++) fa[m] = *(const short8*)(a_rd + m*1280);
    #pragma unroll
    for(int n=0;n<8;n++) fb[n] = *(const short8*)(bb + n*2048);
    #pragma unroll
    for(int m=0;m<4;m++)
      #pragma unroll
      for(int n=0;n<8;n++)
        acc[m][n] = __builtin_amdgcn_mfma_f32_16x16x32_bf16(fa[m], fb[n], acc[m][n], 0,0,0);
  }

  // epilogue: partial[cb*2+wc][compacted row] over wave's 128 cols
  float av[8], ev[8];
  #pragma unroll
  for(int n=0;n<8;n++){
    const int col = cb*256 + wc*128 + n*16 + lm;
    av[n] = avec[bidx*DIM + col];
    ev[n] = energy[col];
  }
  #pragma unroll
  for(int m=0;m<4;m++){
    float rs[4];
    #pragma unroll
    for(int j=0;j<4;j++){
      float s = 0.f;
      #pragma unroll
      for(int n=0;n<8;n++) s += ev[n]*fast_tanh(av[n] + acc[m][n][j]);
      s += __shfl_xor(s,1); s += __shfl_xor(s,2);
      s += __shfl_xor(s,4); s += __shfl_xor(s,8);
      rs[j] = s;
    }
    if(lm == 0){
      float4 st = {rs[0], rs[1], rs[2], rs[3]};
      *(float4*)(partial + (size_t)(cb*2+wc)*NM + bidx*NS + tile*128 + wr*64 + m*16 + lk*4) = st;
    }
  }
}

// ---------------- select over compacted rows; scatter scores to orig ids ------
__global__ void k_select(const float* __restrict__ partial,
                         const int* __restrict__ cidx,
                         const int* __restrict__ cnt,
                         float* __restrict__ scores,
                         int* __restrict__ sel_count,
                         int* __restrict__ sel_list){
  const int b = blockIdx.x, t = threadIdx.x;
  const int w = t >> 6, lane = t & 63;
  __shared__ float red[4];
  const int cnt_b = cnt[b];
  float sv[8]; int orig[8];
  float m = -3.4e38f;
  #pragma unroll
  for(int j=0;j<8;j++){
    const int i = j*256 + t;                  // compacted index
    if(i < cnt_b){
      float s = 0.f;
      #pragma unroll
      for(int c=0;c<8;c++) s += partial[(size_t)c*NM + b*NS + i];
      sv[j] = s;
      orig[j] = cidx[b*NS + i];
      scores[b*NS + orig[j]] = s;             // all compacted rows are unmasked
      if(s > m) m = s;
    } else { sv[j] = -3.4e38f; orig[j] = -1; }
  }
  #pragma unroll
  for(int off=1; off<64; off<<=1) m = fmaxf(m, __shfl_xor(m, off));
  if(lane==0) red[w] = m;
  __syncthreads();
  m = fmaxf(fmaxf(red[0],red[1]), fmaxf(red[2],red[3]));
  const float thr = m - SEL_MARGIN;
  #pragma unroll
  for(int j=0;j<8;j++){
    if(orig[j] >= 0 && sv[j] > thr){
      int slot = atomicAdd(&sel_count[b], 1);
      if(slot < CAP) sel_list[b*CAP + slot] = orig[j];
    }
  }
}

// ---------------- phase-2: exact 3-pass rescoring of selected rows ------------
__global__ __launch_bounds__(256)
void k_phase2(const float* __restrict__ xs,
              const char* __restrict__ imgf,
              const float* __restrict__ avec,
              const float* __restrict__ energy,
              const int* __restrict__ sel_count,
              const int* __restrict__ sel_list,
              float* __restrict__ p2buf){
  __shared__ us16 A2[32][80];     // hi bytes [0,64), lo at +80, row stride 160B
  __shared__ float s2[4][32];
  const int b = blockIdx.x >> 4, cb = blockIdx.x & 15;
  const int t = threadIdx.x, w = t >> 6, lane = t & 63;
  const int lm = lane & 15, lk = lane >> 4;
  const int ct = cb*4 + w;                    // ct16 index 0..63
  const int col = ct*16 + lm;
  const float av  = avec[b*DIM + col];
  const float evv = energy[col];
  char* lds = (char*)&A2[0][0];
  const int count = min(sel_count[b], CAP);
  const int ri = t >> 3, seg = t & 7;
  // 2-bit XOR key: must stay inside the 64-byte hi field (R6 lesson)
  const int wbyte = ri*160 + ((seg*8) ^ ((ri&3)<<4));
  const char* a_rd = lds + lm*160 + ((lk*16) ^ ((lm&3)<<4));

  for(int c0 = 0; c0 < count; c0 += 32){
    const int li = c0 + ri;
    const int row = sel_list[b*CAP + min(li, count-1)];
    const float* rp = xs + ((size_t)b*NS + row)*DIM + seg*4;
    f32x4 acc[2];
    acc[0] = (f32x4){0.f,0.f,0.f,0.f};
    acc[1] = (f32x4){0.f,0.f,0.f,0.f};
    for(int kt=0; kt<32; kt++){
      __syncthreads();                        // prior kt's frag reads consumed
      float4 v = *(const float4*)(rp + kt*32);
      float fv[4] = {v.x, v.y, v.z, v.w};
      us16x4 hi, lo;
      #pragma unroll
      for(int e=0;e<4;e++){
        short a, l; split_bf16(fv[e], a, l);
        hi[e] = (us16)a; lo[e] = (us16)l;
      }
      *(us16x4*)(lds + wbyte)      = hi;
      *(us16x4*)(lds + wbyte + 80) = lo;
      __syncthreads();
      const char* fbb = imgf + ((size_t)(kt*64 + ct)*2)*1024 + lane*16;
      short8 bh = *(const short8*)(fbb);
      short8 bl = *(const short8*)(fbb + 1024);
      short8 fah[2], fal[2];
      #pragma unroll
      for(int m=0;m<2;m++){
        fah[m] = *(const short8*)(a_rd + m*2560);
        fal[m] = *(const short8*)(a_rd + m*2560 + 80);
      }
      #pragma unroll
      for(int m=0;m<2;m++)
        acc[m] = __builtin_amdgcn_mfma_f32_16x16x32_bf16(fah[m], bh, acc[m], 0,0,0);
      #pragma unroll
      for(int m=0;m<2;m++)
        acc[m] = __builtin_amdgcn_mfma_f32_16x16x32_bf16(fah[m], bl, acc[m], 0,0,0);
      #pragma unroll
      for(int m=0;m<2;m++)
        acc[m] = __builtin_amdgcn_mfma_f32_16x16x32_bf16(fal[m], bh, acc[m], 0,0,0);
    }
    float s[2][4];
    #pragma unroll
    for(int m=0;m<2;m++)
      #pragma unroll
      for(int j=0;j<4;j++){
        float v = evv * fast_tanh(av + acc[m][j]);
        v += __shfl_xor(v,1); v += __shfl_xor(v,2);
        v += __shfl_xor(v,4); v += __shfl_xor(v,8);
        s[m][j] = v;
      }
    __syncthreads();
    if(lm == 0){
      #pragma unroll
      for(int m=0;m<2;m++)
        #pragma unroll
        for(int j=0;j<4;j++) s2[w][m*16 + lk*4 + j] = s[m][j];
    }
    __syncthreads();
    if(t < 32){
      float sum = s2[0][t] + s2[1][t] + s2[2][t] + s2[3][t];
      p2buf[((size_t)b*16 + cb)*CAP + c0 + t] = sum;
    }
  }
}

// ------ masked softmax + exact-score scatter + deterministic significant list -
__global__ void k_softmax(const float* __restrict__ scores,
                          const float* __restrict__ p2buf,
                          const int* __restrict__ sel_count,
                          const int* __restrict__ sel_list,
                          const int* __restrict__ mask,
                          float* __restrict__ attn,
                          int* __restrict__ slist2,
                          float* __restrict__ sval2,
                          int* __restrict__ scount2){
  const int b = blockIdx.x, t = threadIdx.x;
  const int w = t >> 6, lane = t & 63;
  __shared__ float sc[NS];      // 8KB: corrected scores
  __shared__ float red[4];
  __shared__ int tc[256];
  __shared__ int tot;
  #pragma unroll
  for(int j=0;j<8;j++) sc[j*256+t] = scores[b*NS + j*256 + t];
  __syncthreads();
  const int count = min(sel_count[b], CAP);
  for(int s0 = t; s0 < count; s0 += 256){
    float s = 0.f;
    #pragma unroll
    for(int c=0;c<16;c++) s += p2buf[((size_t)b*16 + c)*CAP + s0];
    sc[sel_list[b*CAP + s0]] = s;
  }
  __syncthreads();
  float sv[8]; int mv[8];
  float m = -3.4e38f;
  #pragma unroll
  for(int j=0;j<8;j++){
    const int i = j*256 + t;
    sv[j] = sc[i];
    mv[j] = mask[b*NS + i];
    if(mv[j] && sv[j] > m) m = sv[j];
  }
  #pragma unroll
  for(int off=1; off<64; off<<=1) m = fmaxf(m, __shfl_xor(m, off));
  if(lane==0) red[w] = m;
  __syncthreads();
  m = fmaxf(fmaxf(red[0],red[1]), fmaxf(red[2],red[3]));
  __syncthreads();
  float ev[8]; float l = 0.f;
  #pragma unroll
  for(int j=0;j<8;j++){
    ev[j] = mv[j] ? __builtin_exp2f((sv[j]-m)*1.4426950408889634f) : 0.f;
    l += ev[j];
  }
  #pragma unroll
  for(int off=1; off<64; off<<=1) l += __shfl_xor(l, off);
  if(lane==0) red[w] = l;
  __syncthreads();
  l = red[0]+red[1]+red[2]+red[3];
  const float inv = 1.0f/l;
  // write attn + deterministic ordered list of significant rows (attn > 1e-9)
  float av8[8]; int sig[8]; int c = 0;
  #pragma unroll
  for(int j=0;j<8;j++){
    av8[j] = ev[j]*inv;
    attn[b*NS + j*256 + t] = av8[j];
    sig[j] = (av8[j] > 1e-9f) ? 1 : 0;
    c += sig[j];
  }
  tc[t] = c;
  __syncthreads();
  for(int d=1; d<256; d<<=1){            // Hillis-Steele inclusive scan
    int v = tc[t];
    int add = (t >= d) ? tc[t-d] : 0;
    __syncthreads();
    tc[t] = v + add;
    __syncthreads();
  }
  const int excl = tc[t] - c;
  if(t == 255) tot = tc[t];
  __syncthreads();
  int pos = excl;
  #pragma unroll
  for(int j=0;j<8;j++){
    if(sig[j]){
      slist2[b*NS + pos] = j*256 + t;
      sval2 [b*NS + pos] = av8[j];
      pos++;
    }
  }
  if(t == 0) scount2[b] = tot;
}

// ---- ctx over significant rows (deterministic order), 128 blocks -------------
// block = (b, ch): cols ch*256..+256; per-output-d summation order = j ascending
// (bit-identical to the 32-block version; column split doesn't reorder sums)
__global__ void k_ctx(const int* __restrict__ slist2,
                      const float* __restrict__ sval2,
                      const int* __restrict__ scount2,
                      const float* __restrict__ xs,
                      float* __restrict__ ctx){
  const int b = blockIdx.x >> 2, ch = blockIdx.x & 3;
  const int t = threadIdx.x;
  __shared__ int   rows[NS];    // 8KB
  __shared__ float aw[NS];      // 8KB
  const int n = scount2[b];
  for(int i = t; i < n; i += 256){
    rows[i] = slist2[b*NS + i];
    aw[i]   = sval2 [b*NS + i];
  }
  __syncthreads();
  float acc = 0.f;
  const int col = ch*256 + t;
  const float* xb = xs + (size_t)b*NS*DIM + col;
  for(int j=0;j<n;j++){
    acc += aw[j] * xb[(size_t)rows[j]*DIM];
  }
  ctx[b*DIM + col] = acc;
}

extern "C" void kernel_launch(void* const* d_in, const int* in_sizes, int n_in,
                              void* d_out, int out_size, void* d_ws, size_t ws_size,
                              hipStream_t stream) {
  const float* kin    = (const float*)d_in[0];   // [32,1024]
  const float* xs     = (const float*)d_in[1];   // [32,2048,1024]
  const int*   mask   = (const int*)d_in[2];     // [32,2048]
  const float* wa     = (const float*)d_in[3];   // [1024,1024]
  const float* wb     = (const float*)d_in[4];   // [1024,1024]
  const float* energy = (const float*)d_in[5];   // [1024]
  float* out  = (float*)d_out;
  float* ctx  = out;            // [32,1024]
  float* attn = out + NB*DIM;   // [32,2048]

  char* ws = (char*)d_ws;
  float* partial   = (float*)(ws);                       // 2 MB    @ 0
  float* avec      = (float*)(ws + 2097152);             // 128 KB
  float* scores    = (float*)(ws + 2228224);             // 256 KB
  int*   slist2    = (int*)(ws + 2490368);               // 256 KB
  float* sval2     = (float*)(ws + 2752512);             // 256 KB
  int*   scount2   = (int*)(ws + 3014656);               // 128 B
  char*  imgf      = ws + 3538944;                       // 4 MB (frag hi/lo)
  char*  img1      = ws + 7733248;                       // 2 MB (gload hi, BK=32)
  int*   sel_count = (int*)(ws + 9830400);               // 128 B
  int*   sel_list  = (int*)(ws + 9830528);               // 32 KB
  float* p2buf     = (float*)(ws + 9863296);             // 512 KB
  int*   cidx      = (int*)(ws + 10387584);              // 256 KB
  int*   cnt       = (int*)(ws + 10649728);              // 128 B

  k_prep       <<<1696, 256, 0, stream>>>(wb, kin, wa, mask, imgf, img1, avec,
                                          cidx, cnt, sel_count);
  k_gemm_approx<<<2048, 256, 0, stream>>>(xs, img1, avec, energy, cidx, cnt, partial);
  k_select     <<<NB, 256, 0, stream>>>(partial, cidx, cnt, scores, sel_count, sel_list);
  k_phase2     <<<512, 256, 0, stream>>>(xs, imgf, avec, energy, sel_count, sel_list, p2buf);
  k_softmax    <<<NB, 256, 0, stream>>>(scores, p2buf, sel_count, sel_list, mask, attn,
                                        slist2, sval2, scount2);
  k_ctx        <<<128, 256, 0, stream>>>(slist2, sval2, scount2, xs, ctx);
}

// Round 17
// 254.247 us; speedup vs baseline: 4.3072x; 1.0052x over previous
//
#include <hip/hip_runtime.h>
#include <hip/hip_bf16.h>

#define NB 32
#define NS 2048
#define DIM 1024
#define NM (NB*NS)   // 65536 rows
#define CAP 256      // max rescored rows per batch
#define SEL_MARGIN 24.0f

typedef __attribute__((ext_vector_type(8))) short short8;
typedef __attribute__((ext_vector_type(4))) float f32x4;
typedef __attribute__((ext_vector_type(4))) unsigned short us16x4;
typedef unsigned short us16;
typedef unsigned int   u32;
typedef __attribute__((address_space(3))) void lds_void;
typedef __attribute__((address_space(1))) void glb_void;

__device__ __forceinline__ void gload16(const void* g, void* l){
  __builtin_amdgcn_global_load_lds((const glb_void*)g, (lds_void*)l, 16, 0, 0);
}

__device__ __forceinline__ float fast_tanh(float x){
  float e = __builtin_exp2f(x * 2.8853900817779268f); // e^{2x}
  return 1.0f - 2.0f/(e + 1.0f);
}

__device__ __forceinline__ void split_bf16(float x, short &hi, short &lo){
  u32 u = __float_as_uint(x);
  float hf = __uint_as_float(u & 0xFFFF0000u);
  hi = (short)(u >> 16);
  lo = (short)(__float_as_uint(x - hf) >> 16);
}

// ---------------- fused prep: wb images + avec + mask compaction --------------
__global__ void k_prep(const float* __restrict__ wb,
                       const float* __restrict__ kin,
                       const float* __restrict__ wa,
                       const int* __restrict__ mask,
                       char* __restrict__ imgf,
                       char* __restrict__ img1,
                       float* __restrict__ avec,
                       int* __restrict__ cidx,
                       int* __restrict__ cnt,
                       int* __restrict__ sel_count){
  __shared__ float4 kl[256];
  __shared__ int tc[256];
  __shared__ int tot;
  const int h = blockIdx.x, t = threadIdx.x;
  if(h == 0 && t < NB) sel_count[t] = 0;
  if(h < 1024){
    // phase-2 B image: 16B slot = ((kt*64 + ct16)*2 + hl)*64 + lane
    const int tid = h*256 + t;
    const int kt   = tid >> 13;
    const int ct16 = (tid >> 7) & 63;
    const int hl   = (tid >> 6) & 1;
    const int lane = tid & 63;
    const int col  = ct16*16 + (lane & 15);
    const int k0   = kt*32 + (lane >> 4)*8;
    const float* src = wb + (size_t)col*DIM + k0;
    float4 v0 = *(const float4*)src;
    float4 v1 = *(const float4*)(src + 4);
    float fv[8] = {v0.x,v0.y,v0.z,v0.w,v1.x,v1.y,v1.z,v1.w};
    short8 out;
    #pragma unroll
    for(int j=0;j<8;j++){
      short hi,lo; split_bf16(fv[j],hi,lo);
      out[j] = hl ? lo : hi;
    }
    *(short8*)(imgf + (size_t)tid*16) = out;
  } else if(h < 1536){
    // phase-1 B image = [kt(32)][cb(4)][16KB]; byte B: row=B>>7, inner=B&127,
    // ix = inner ^ ((row&7)<<4): col = cb*256 + (ix>>6)*128 + row,
    // k = kt*32 + ((ix>>4)&3)*8 + (B&15)/2 (hi bf16)
    const int tid = (h-1024)*256 + t;
    const int tile = tid >> 10;
    const int kt = tile >> 2, cb = tile & 3;
    const int byt = (tid & 1023) * 16;
    const int row = byt >> 7, inner = byt & 127;
    const int ix = inner ^ ((row & 7) << 4);
    const int colhi = ix >> 6, lkk = (ix >> 4) & 3;
    const int col = cb*256 + colhi*128 + row;
    const float* src = wb + (size_t)col*DIM + kt*32 + lkk*8;
    float4 v0 = *(const float4*)src;
    float4 v1 = *(const float4*)(src + 4);
    float fv[8] = {v0.x,v0.y,v0.z,v0.w,v1.x,v1.y,v1.z,v1.w};
    short8 out;
    #pragma unroll
    for(int j=0;j<8;j++) out[j] = (short)(__float_as_uint(fv[j]) >> 16);
    *(short8*)(img1 + (size_t)tid*16) = out;
  } else if(h < 1664){
    const int hb = h - 1536;
    const int b = hb >> 2, oc = hb & 3;
    kl[t] = *(const float4*)(kin + b*DIM + t*4);
    __syncthreads();
    const int o = oc*256 + t;
    const float4* wrow = (const float4*)(wa + (size_t)o*DIM);
    float acc = 0.f;
    for(int i=0;i<256;i++){
      float4 wv = wrow[i]; float4 kk = kl[i];
      acc += wv.x*kk.x + wv.y*kk.y + wv.z*kk.z + wv.w*kk.w;
    }
    avec[b*DIM + o] = acc;
  } else {
    // ---- stable compaction of unmasked rows for batch b ----
    const int b = h - 1664;
    int mv[8]; int c = 0;
    #pragma unroll
    for(int e=0;e<8;e++){ mv[e] = mask[b*NS + t*8 + e]; c += (mv[e] ? 1 : 0); }
    tc[t] = c;
    __syncthreads();
    for(int d=1; d<256; d<<=1){          // Hillis-Steele inclusive scan
      int v = tc[t];
      int add = (t >= d) ? tc[t-d] : 0;
      __syncthreads();
      tc[t] = v + add;
      __syncthreads();
    }
    const int excl = tc[t] - c;
    if(t == 255) tot = tc[t];
    __syncthreads();
    int pos = excl;
    #pragma unroll
    for(int e=0;e<8;e++){
      if(mv[e]) cidx[b*NS + (pos++)] = t*8 + e;
    }
    const int total = tot;
    if(t == 0) cnt[b] = total;
    for(int p = total + t; p < NS; p += 256) cidx[b*NS + p] = 0;  // safe pad
  }
}

// truncate-store A tile (16 f32) into buffer at DST (R13-verified layout:
// 80B rows, 2-bit XOR key on the 64B hi field)
#define SPLIT_STORE_A(DST, AR0,AR1,AR2,AR3)                                     \
  {                                                                             \
    float fv[16];                                                               \
    *(float4*)(fv+0)=AR0; *(float4*)(fv+4)=AR1;                                 \
    *(float4*)(fv+8)=AR2; *(float4*)(fv+12)=AR3;                                \
    short8 h0, h1;                                                              \
    _Pragma("unroll")                                                           \
    for(int j=0;j<8;j++){ h0[j] = (short)(__float_as_uint(fv[j])>>16);          \
                          h1[j] = (short)(__float_as_uint(fv[8+j])>>16); }      \
    char* abase = (DST) + sr*80;                                                \
    const int swz = (sr & 3) << 4;                                              \
    *(short8*)(abase + ((sh*32     ) ^ swz)) = h0;                              \
    *(short8*)(abase + ((sh*32 + 16) ^ swz)) = h1;                              \
  }

// ---------------- phase-1: 1-pass truncated-bf16 GEMM over COMPACTED rows -----
// R13 algorithm + T3 minimum-2-phase schedule (catalog §5.5): A AND B double-
// buffered, staging issued BEFORE frag reads + MFMA, waits after MFMA, ONE
// s_barrier per kt. __launch_bounds__(256,2) mandatory (R10/R14: acc=128 AGPR;
// any allocator cap below ~232 regs/wave spills the accumulator).
// R17 fix vs R16: B frag-read buffer stride is 16384 B (128x64 us16), not 32768.
__global__ __launch_bounds__(256,2)
void k_gemm_approx(const float* __restrict__ xs,
                   const char* __restrict__ img1,
                   const float* __restrict__ avec,
                   const float* __restrict__ energy,
                   const int* __restrict__ cidx,
                   const int* __restrict__ cnt,
                   float* __restrict__ partial){
  __shared__ us16 Abuf[2][128][40];   // 2 x 10240 B, reg->split-store
  __shared__ us16 Bbuf[2][128][64];   // 2 x 16384 B, global_load_lds

  const int h = blockIdx.x;                   // 2048 blocks
  int bidx, tile, cb;
  if(h < 1152){                               // dense: 32 b x 9 t x 4 cb
    const int q = h >> 3;                     // 0..143
    cb = q & 3;
    const int pair = (h & 7)*36 + (q >> 2);   // XCD h%8 owns pairs [36x,36x+36)
    bidx = pair / 9; tile = pair % 9;
  } else {                                    // rare region: tiles 9..15
    const int h2 = h - 1152;
    bidx = h2 / 28; tile = 9 + ((h2 % 28) >> 2); cb = h2 & 3;
  }
  if(tile*128 >= cnt[bidx]) return;           // tile beyond unmasked count
  const int t  = threadIdx.x;
  const int w  = t >> 6, lane = t & 63;
  const int wr = w >> 1, wc = w & 1;          // wave tile: 64 rows x 128 cols
  const int lm = lane & 15, lk = lane >> 4;
  const int sr = t >> 1, sh = t & 1;

  const int orig = cidx[bidx*NS + tile*128 + sr];   // gathered source row
  const float* ap = xs + ((size_t)bidx*NS + orig)*DIM + sh*16;
  const char*  bsrc = img1;                   // + (kt*4+cb)*16384

  const int a_ro = (wr*64 + lm)*80 + ((lk*16) ^ ((lm&3)<<4));
  const int b_ro = lm*128 + ((wc*64 + lk*16) ^ ((lm&7)<<4));
  const char* ab_base = (const char*)&Abuf[0][0][0];
  const char* bb_base = (const char*)&Bbuf[0][0][0];

  f32x4 acc[4][8];
  #pragma unroll
  for(int m=0;m<4;m++)
    #pragma unroll
    for(int n=0;n<8;n++) acc[m][n] = (f32x4){0.f,0.f,0.f,0.f};

  // ---- prologue: stage tile 0 into buffers [0]; preload A(1) ----
  float4 ar0 = *(const float4*)(ap+0),  ar1 = *(const float4*)(ap+4);
  float4 ar2 = *(const float4*)(ap+8),  ar3 = *(const float4*)(ap+12);
  {
    const char* gs = bsrc + (size_t)cb*16384 + t*16;
    char* ld = (char*)&Bbuf[0][0][0] + t*16;
    #pragma unroll
    for(int c=0;c<4;c++) gload16(gs + c*4096, ld + c*4096);
  }
  SPLIT_STORE_A((char*)&Abuf[0][0][0], ar0, ar1, ar2, ar3);  // waits A(0) regs
  {
    const float* a1 = ap + 32;
    ar0 = *(const float4*)(a1+0);  ar1 = *(const float4*)(a1+4);
    ar2 = *(const float4*)(a1+8);  ar3 = *(const float4*)(a1+12);
  }
  // in flight: [B(0)x4, A(1)x4] -> B(0) landed, A(1) keeps flying
  asm volatile("s_waitcnt vmcnt(4) lgkmcnt(0)" ::: "memory");
  __builtin_amdgcn_sched_barrier(0);
  __builtin_amdgcn_s_barrier();

  for(int kt=0; kt<32; kt++){
    const int cur = kt & 1;
    // ---- stage tile kt+1 into [1-cur] (issued BEFORE frag reads / MFMA) ----
    if(kt < 31){
      const char* gs = bsrc + (size_t)((kt+1)*4 + cb)*16384 + t*16;   // B first
      char* ld = (char*)&Bbuf[cur^1][0][0] + t*16;
      #pragma unroll
      for(int c=0;c<4;c++) gload16(gs + c*4096, ld + c*4096);
      // split A(kt+1): implicit wait vmcnt(4) (A(kt+1) older than B(kt+1))
      SPLIT_STORE_A((char*)&Abuf[cur^1][0][0], ar0, ar1, ar2, ar3);
    }
    if(kt < 30){                              // A(kt+2) -> ar (WAR after split)
      const float* a2 = ap + (kt+2)*32;
      ar0 = *(const float4*)(a2+0);  ar1 = *(const float4*)(a2+4);
      ar2 = *(const float4*)(a2+8);  ar3 = *(const float4*)(a2+12);
    }
    // ---- frag reads of tile kt from [cur] ----
    short8 fa[4], fb[8];
    const char* ar_ = ab_base + cur*10240 + a_ro;
    const char* bb_ = bb_base + cur*16384 + b_ro;   // R17 FIX: was cur*32768
    #pragma unroll
    for(int m=0;m<4;m++) fa[m] = *(const short8*)(ar_ + m*1280);
    #pragma unroll
    for(int n=0;n<8;n++) fb[n] = *(const short8*)(bb_ + n*2048);
    asm volatile("s_waitcnt lgkmcnt(0)" ::: "memory");
    __builtin_amdgcn_sched_barrier(0);
    __builtin_amdgcn_s_setprio(1);
    #pragma unroll
    for(int m=0;m<4;m++)
      #pragma unroll
      for(int n=0;n<8;n++)
        acc[m][n] = __builtin_amdgcn_mfma_f32_16x16x32_bf16(fa[m], fb[n], acc[m][n], 0,0,0);
    __builtin_amdgcn_s_setprio(0);
    // ---- ONE barrier per kt: B(kt+1) landed, A(kt+2) keeps flying ----
    if(kt < 31){
      if(kt < 30) asm volatile("s_waitcnt vmcnt(4)" ::: "memory");
      else        asm volatile("s_waitcnt vmcnt(0)" ::: "memory");
      __builtin_amdgcn_sched_barrier(0);
      __builtin_amdgcn_s_barrier();
    }
  }

  // epilogue: partial[cb*2+wc][compacted row] over wave's 128 cols
  float av[8], ev[8];
  #pragma unroll
  for(int n=0;n<8;n++){
    const int col = cb*256 + wc*128 + n*16 + lm;
    av[n] = avec[bidx*DIM + col];
    ev[n] = energy[col];
  }
  #pragma unroll
  for(int m=0;m<4;m++){
    float rs[4];
    #pragma unroll
    for(int j=0;j<4;j++){
      float s = 0.f;
      #pragma unroll
      for(int n=0;n<8;n++) s += ev[n]*fast_tanh(av[n] + acc[m][n][j]);
      s += __shfl_xor(s,1); s += __shfl_xor(s,2);
      s += __shfl_xor(s,4); s += __shfl_xor(s,8);
      rs[j] = s;
    }
    if(lm == 0){
      float4 st = {rs[0], rs[1], rs[2], rs[3]};
      *(float4*)(partial + (size_t)(cb*2+wc)*NM + bidx*NS + tile*128 + wr*64 + m*16 + lk*4) = st;
    }
  }
}

// ---------------- select over compacted rows; scatter scores to orig ids ------
__global__ void k_select(const float* __restrict__ partial,
                         const int* __restrict__ cidx,
                         const int* __restrict__ cnt,
                         float* __restrict__ scores,
                         int* __restrict__ sel_count,
                         int* __restrict__ sel_list){
  const int b = blockIdx.x, t = threadIdx.x;
  const int w = t >> 6, lane = t & 63;
  __shared__ float red[4];
  const int cnt_b = cnt[b];
  float sv[8]; int orig[8];
  float m = -3.4e38f;
  #pragma unroll
  for(int j=0;j<8;j++){
    const int i = j*256 + t;                  // compacted index
    if(i < cnt_b){
      float s = 0.f;
      #pragma unroll
      for(int c=0;c<8;c++) s += partial[(size_t)c*NM + b*NS + i];
      sv[j] = s;
      orig[j] = cidx[b*NS + i];
      scores[b*NS + orig[j]] = s;             // all compacted rows are unmasked
      if(s > m) m = s;
    } else { sv[j] = -3.4e38f; orig[j] = -1; }
  }
  #pragma unroll
  for(int off=1; off<64; off<<=1) m = fmaxf(m, __shfl_xor(m, off));
  if(lane==0) red[w] = m;
  __syncthreads();
  m = fmaxf(fmaxf(red[0],red[1]), fmaxf(red[2],red[3]));
  const float thr = m - SEL_MARGIN;
  #pragma unroll
  for(int j=0;j<8;j++){
    if(orig[j] >= 0 && sv[j] > thr){
      int slot = atomicAdd(&sel_count[b], 1);
      if(slot < CAP) sel_list[b*CAP + slot] = orig[j];
    }
  }
}

// ---------------- phase-2: exact 3-pass rescoring of selected rows ------------
__global__ __launch_bounds__(256)
void k_phase2(const float* __restrict__ xs,
              const char* __restrict__ imgf,
              const float* __restrict__ avec,
              const float* __restrict__ energy,
              const int* __restrict__ sel_count,
              const int* __restrict__ sel_list,
              float* __restrict__ p2buf){
  __shared__ us16 A2[32][80];     // hi bytes [0,64), lo at +80, row stride 160B
  __shared__ float s2[4][32];
  const int b = blockIdx.x >> 4, cb = blockIdx.x & 15;
  const int t = threadIdx.x, w = t >> 6, lane = t & 63;
  const int lm = lane & 15, lk = lane >> 4;
  const int ct = cb*4 + w;                    // ct16 index 0..63
  const int col = ct*16 + lm;
  const float av  = avec[b*DIM + col];
  const float evv = energy[col];
  char* lds = (char*)&A2[0][0];
  const int count = min(sel_count[b], CAP);
  const int ri = t >> 3, seg = t & 7;
  // 2-bit XOR key: must stay inside the 64-byte hi field (R6 lesson)
  const int wbyte = ri*160 + ((seg*8) ^ ((ri&3)<<4));
  const char* a_rd = lds + lm*160 + ((lk*16) ^ ((lm&3)<<4));

  for(int c0 = 0; c0 < count; c0 += 32){
    const int li = c0 + ri;
    const int row = sel_list[b*CAP + min(li, count-1)];
    const float* rp = xs + ((size_t)b*NS + row)*DIM + seg*4;
    f32x4 acc[2];
    acc[0] = (f32x4){0.f,0.f,0.f,0.f};
    acc[1] = (f32x4){0.f,0.f,0.f,0.f};
    for(int kt=0; kt<32; kt++){
      __syncthreads();                        // prior kt's frag reads consumed
      float4 v = *(const float4*)(rp + kt*32);
      float fv[4] = {v.x, v.y, v.z, v.w};
      us16x4 hi, lo;
      #pragma unroll
      for(int e=0;e<4;e++){
        short a, l; split_bf16(fv[e], a, l);
        hi[e] = (us16)a; lo[e] = (us16)l;
      }
      *(us16x4*)(lds + wbyte)      = hi;
      *(us16x4*)(lds + wbyte + 80) = lo;
      __syncthreads();
      const char* fbb = imgf + ((size_t)(kt*64 + ct)*2)*1024 + lane*16;
      short8 bh = *(const short8*)(fbb);
      short8 bl = *(const short8*)(fbb + 1024);
      short8 fah[2], fal[2];
      #pragma unroll
      for(int m=0;m<2;m++){
        fah[m] = *(const short8*)(a_rd + m*2560);
        fal[m] = *(const short8*)(a_rd + m*2560 + 80);
      }
      #pragma unroll
      for(int m=0;m<2;m++)
        acc[m] = __builtin_amdgcn_mfma_f32_16x16x32_bf16(fah[m], bh, acc[m], 0,0,0);
      #pragma unroll
      for(int m=0;m<2;m++)
        acc[m] = __builtin_amdgcn_mfma_f32_16x16x32_bf16(fah[m], bl, acc[m], 0,0,0);
      #pragma unroll
      for(int m=0;m<2;m++)
        acc[m] = __builtin_amdgcn_mfma_f32_16x16x32_bf16(fal[m], bh, acc[m], 0,0,0);
    }
    float s[2][4];
    #pragma unroll
    for(int m=0;m<2;m++)
      #pragma unroll
      for(int j=0;j<4;j++){
        float v = evv * fast_tanh(av + acc[m][j]);
        v += __shfl_xor(v,1); v += __shfl_xor(v,2);
        v += __shfl_xor(v,4); v += __shfl_xor(v,8);
        s[m][j] = v;
      }
    __syncthreads();
    if(lm == 0){
      #pragma unroll
      for(int m=0;m<2;m++)
        #pragma unroll
        for(int j=0;j<4;j++) s2[w][m*16 + lk*4 + j] = s[m][j];
    }
    __syncthreads();
    if(t < 32){
      float sum = s2[0][t] + s2[1][t] + s2[2][t] + s2[3][t];
      p2buf[((size_t)b*16 + cb)*CAP + c0 + t] = sum;
    }
  }
}

// ------ masked softmax + exact-score scatter + deterministic significant list -
__global__ void k_softmax(const float* __restrict__ scores,
                          const float* __restrict__ p2buf,
                          const int* __restrict__ sel_count,
                          const int* __restrict__ sel_list,
                          const int* __restrict__ mask,
                          float* __restrict__ attn,
                          int* __restrict__ slist2,
                          float* __restrict__ sval2,
                          int* __restrict__ scount2){
  const int b = blockIdx.x, t = threadIdx.x;
  const int w = t >> 6, lane = t & 63;
  __shared__ float sc[NS];      // 8KB: corrected scores
  __shared__ float red[4];
  __shared__ int tc[256];
  __shared__ int tot;
  #pragma unroll
  for(int j=0;j<8;j++) sc[j*256+t] = scores[b*NS + j*256 + t];
  __syncthreads();
  const int count = min(sel_count[b], CAP);
  for(int s0 = t; s0 < count; s0 += 256){
    float s = 0.f;
    #pragma unroll
    for(int c=0;c<16;c++) s += p2buf[((size_t)b*16 + c)*CAP + s0];
    sc[sel_list[b*CAP + s0]] = s;
  }
  __syncthreads();
  float sv[8]; int mv[8];
  float m = -3.4e38f;
  #pragma unroll
  for(int j=0;j<8;j++){
    const int i = j*256 + t;
    sv[j] = sc[i];
    mv[j] = mask[b*NS + i];
    if(mv[j] && sv[j] > m) m = sv[j];
  }
  #pragma unroll
  for(int off=1; off<64; off<<=1) m = fmaxf(m, __shfl_xor(m, off));
  if(lane==0) red[w] = m;
  __syncthreads();
  m = fmaxf(fmaxf(red[0],red[1]), fmaxf(red[2],red[3]));
  __syncthreads();
  float ev[8]; float l = 0.f;
  #pragma unroll
  for(int j=0;j<8;j++){
    ev[j] = mv[j] ? __builtin_exp2f((sv[j]-m)*1.4426950408889634f) : 0.f;
    l += ev[j];
  }
  #pragma unroll
  for(int off=1; off<64; off<<=1) l += __shfl_xor(l, off);
  if(lane==0) red[w] = l;
  __syncthreads();
  l = red[0]+red[1]+red[2]+red[3];
  const float inv = 1.0f/l;
  // write attn + deterministic ordered list of significant rows (attn > 1e-9)
  float av8[8]; int sig[8]; int c = 0;
  #pragma unroll
  for(int j=0;j<8;j++){
    av8[j] = ev[j]*inv;
    attn[b*NS + j*256 + t] = av8[j];
    sig[j] = (av8[j] > 1e-9f) ? 1 : 0;
    c += sig[j];
  }
  tc[t] = c;
  __syncthreads();
  for(int d=1; d<256; d<<=1){            // Hillis-Steele inclusive scan
    int v = tc[t];
    int add = (t >= d) ? tc[t-d] : 0;
    __syncthreads();
    tc[t] = v + add;
    __syncthreads();
  }
  const int excl = tc[t] - c;
  if(t == 255) tot = tc[t];
  __syncthreads();
  int pos = excl;
  #pragma unroll
  for(int j=0;j<8;j++){
    if(sig[j]){
      slist2[b*NS + pos] = j*256 + t;
      sval2 [b*NS + pos] = av8[j];
      pos++;
    }
  }
  if(t == 0) scount2[b] = tot;
}

// ---- ctx over significant rows (deterministic order), 128 blocks -------------
__global__ void k_ctx(const int* __restrict__ slist2,
                      const float* __restrict__ sval2,
                      const int* __restrict__ scount2,
                      const float* __restrict__ xs,
                      float* __restrict__ ctx){
  const int b = blockIdx.x >> 2, ch = blockIdx.x & 3;
  const int t = threadIdx.x;
  __shared__ int   rows[NS];    // 8KB
  __shared__ float aw[NS];      // 8KB
  const int n = scount2[b];
  for(int i = t; i < n; i += 256){
    rows[i] = slist2[b*NS + i];
    aw[i]   = sval2 [b*NS + i];
  }
  __syncthreads();
  float acc = 0.f;
  const int col = ch*256 + t;
  const float* xb = xs + (size_t)b*NS*DIM + col;
  for(int j=0;j<n;j++){
    acc += aw[j] * xb[(size_t)rows[j]*DIM];
  }
  ctx[b*DIM + col] = acc;
}

extern "C" void kernel_launch(void* const* d_in, const int* in_sizes, int n_in,
                              void* d_out, int out_size, void* d_ws, size_t ws_size,
                              hipStream_t stream) {
  const float* kin    = (const float*)d_in[0];   // [32,1024]
  const float* xs     = (const float*)d_in[1];   // [32,2048,1024]
  const int*   mask   = (const int*)d_in[2];     // [32,2048]
  const float* wa     = (const float*)d_in[3];   // [1024,1024]
  const float* wb     = (const float*)d_in[4];   // [1024,1024]
  const float* energy = (const float*)d_in[5];   // [1024]
  float* out  = (float*)d_out;
  float* ctx  = out;            // [32,1024]
  float* attn = out + NB*DIM;   // [32,2048]

  char* ws = (char*)d_ws;
  float* partial   = (float*)(ws);                       // 2 MB    @ 0
  float* avec      = (float*)(ws + 2097152);             // 128 KB
  float* scores    = (float*)(ws + 2228224);             // 256 KB
  int*   slist2    = (int*)(ws + 2490368);               // 256 KB
  float* sval2     = (float*)(ws + 2752512);             // 256 KB
  int*   scount2   = (int*)(ws + 3014656);               // 128 B
  char*  imgf      = ws + 3538944;                       // 4 MB (frag hi/lo)
  char*  img1      = ws + 7733248;                       // 2 MB (gload hi, BK=32)
  int*   sel_count = (int*)(ws + 9830400);               // 128 B
  int*   sel_list  = (int*)(ws + 9830528);               // 32 KB
  float* p2buf     = (float*)(ws + 9863296);             // 512 KB
  int*   cidx      = (int*)(ws + 10387584);              // 256 KB
  int*   cnt       = (int*)(ws + 10649728);              // 128 B

  k_prep       <<<1696, 256, 0, stream>>>(wb, kin, wa, mask, imgf, img1, avec,
                                          cidx, cnt, sel_count);
  k_gemm_approx<<<2048, 256, 0, stream>>>(xs, img1, avec, energy, cidx, cnt, partial);
  k_select     <<<NB, 256, 0, stream>>>(partial, cidx, cnt, scores, sel_count, sel_list);
  k_phase2     <<<512, 256, 0, stream>>>(xs, imgf, avec, energy, sel_count, sel_list, p2buf);
  k_softmax    <<<NB, 256, 0, stream>>>(scores, p2buf, sel_count, sel_list, mask, attn,
                                        slist2, sval2, scount2);
  k_ctx        <<<128, 256, 0, stream>>>(slist2, sval2, scount2, xs, ctx);
}